// Round 3
// baseline (20035.101 us; speedup 1.0000x reference)
//
#include <hip/hip_runtime.h>
#include <hip/hip_bf16.h>
#include <hip/hip_cooperative_groups.h>

namespace cg = cooperative_groups;

typedef __attribute__((ext_vector_type(8))) short bf16x8;
typedef __attribute__((ext_vector_type(4))) float f32x4;

#define TT 256
#define BB 64
#define HH 1024

static constexpr int NB = 256;   // 128 layer-0 blocks + 128 layer-1 blocks
static constexpr int NT = 512;   // 8 waves per block

__device__ __forceinline__ unsigned short f2bf(float f) {
    unsigned int u = __float_as_uint(f);
    u += 0x7fffu + ((u >> 16) & 1u);   // round-to-nearest-even
    return (unsigned short)(u >> 16);
}
__device__ __forceinline__ float bf2f(unsigned short s) {
    return __uint_as_float(((unsigned int)s) << 16);
}
__device__ __forceinline__ float sigm(float x) { return 1.0f / (1.0f + __expf(-x)); }
__device__ __forceinline__ float tanh_f(float x) {
    float e = __expf(-2.0f * fabsf(x));
    return copysignf((1.0f - e) / (1.0f + e), x);
}

#define MFMA16(a, b, c) __builtin_amdgcn_mfma_f32_16x16x32_bf16((a), (b), (c), 0, 0, 0)

// async global -> LDS, 16B per lane, linear (dest = uniform base + lane*16)
__device__ __forceinline__ void gll16(const void* g, void* l) {
    __builtin_amdgcn_global_load_lds(
        (const __attribute__((address_space(1))) unsigned int*)g,
        (__attribute__((address_space(3))) unsigned int*)l,
        16, 0, 0);
}

// ---------------- prep: bf16 conversions, bias folding, swizzled h-state init ----------------
// swizzled h layout (per 64x1024 state): ushort index = ((k>>8)*64 + b)*256 + (((k&255)>>3 ^ (b&7))<<3) + (k&7)
__global__ void __launch_bounds__(256) prep_kernel(
    const float* __restrict__ inputs, const float* __restrict__ h0in,
    const float* __restrict__ Wx0, const float* __restrict__ bx0,
    const float* __restrict__ Wh0, const float* __restrict__ bh0,
    const float* __restrict__ Wx1, const float* __restrict__ Wh1,
    unsigned short* __restrict__ Wx0b, unsigned short* __restrict__ Wh0b,
    unsigned short* __restrict__ Wx1b, unsigned short* __restrict__ Wh1b,
    unsigned short* __restrict__ inbf, float* __restrict__ bias0,
    unsigned short* __restrict__ h0sw, unsigned short* __restrict__ h1sw)
{
    const long long Nw  = 4194304;   // 4096*1024
    const long long Nin = 16777216;  // 64*256*1024
    const long long total = 4 * Nw + Nin + 4096 + 131072;
    for (long long idx = (long long)blockIdx.x * blockDim.x + threadIdx.x; idx < total;
         idx += (long long)gridDim.x * blockDim.x) {
        if (idx < Nw) {
            Wx0b[idx] = f2bf(Wx0[idx]);
        } else if (idx < 2 * Nw) {
            long long i = idx - Nw;      Wh0b[i] = f2bf(Wh0[i]);
        } else if (idx < 3 * Nw) {
            long long i = idx - 2 * Nw;  Wx1b[i] = f2bf(Wx1[i]);
        } else if (idx < 4 * Nw) {
            long long i = idx - 3 * Nw;  Wh1b[i] = f2bf(Wh1[i]);
        } else if (idx < 4 * Nw + Nin) {
            long long i = idx - 4 * Nw;
            int k = (int)(i & 1023);
            int t = (int)((i >> 10) & 255);
            int b = (int)(i >> 18);
            inbf[((long long)(t * 64 + b) << 10) + k] = f2bf(inputs[i]);
        } else if (idx < 4 * Nw + Nin + 4096) {
            int i = (int)(idx - (4 * Nw + Nin));
            bias0[i] = bx0[i] + bh0[i];
        } else {
            int i = (int)(idx - (4 * Nw + Nin + 4096));   // 0..131071
            int l = i >> 16;
            int b = (i >> 10) & 63;
            int k = i & 1023;
            unsigned short v = f2bf(h0in[i]);
            unsigned short* dst = l ? h1sw : h0sw;
            // init buffer parity 1 (= state at t = -1)
            dst[65536 + ((k >> 8) * 64 + b) * 256 + ((((k & 255) >> 3) ^ (b & 7)) << 3) + (k & 7)] = v;
        }
    }
}

// ---------------- GEMM0: X0pre[t*64+b][n] = inputs@Wx0^T + bias0, bf16 out ----------------
__global__ void __launch_bounds__(256) gemm0_kernel(
    const unsigned short* __restrict__ A,   // [16384][1024] bf16, row = t*64+b
    const unsigned short* __restrict__ Bw,  // [4096][1024] bf16
    const float* __restrict__ bias0,
    unsigned short* __restrict__ X0pre)     // [16384][4096] bf16
{
    __shared__ __align__(16) char smem[32768];
    unsigned short* As = (unsigned short*)smem;            // [128][64] swizzled
    unsigned short* Bs = (unsigned short*)(smem + 16384);  // [128][64] swizzled
    const int tid = threadIdx.x, lane = tid & 63, wave = tid >> 6;
    const int wm = wave >> 1, wn = wave & 1;
    const int mt = blockIdx.x >> 5, nt = blockIdx.x & 31;

    f32x4 acc[4][4];
#pragma unroll
    for (int a = 0; a < 4; ++a)
#pragma unroll
        for (int b = 0; b < 4; ++b) acc[a][b] = (f32x4){0.f, 0.f, 0.f, 0.f};

    for (int kc = 0; kc < 16; ++kc) {
        __syncthreads();
#pragma unroll
        for (int p = 0; p < 4; ++p) {
            int cidx = tid + p * 256;
            int row = cidx >> 3, slot = cidx & 7;
            bf16x8 va = *reinterpret_cast<const bf16x8*>(A + (size_t)(mt * 128 + row) * 1024 + kc * 64 + slot * 8);
            *reinterpret_cast<bf16x8*>((char*)As + row * 128 + ((slot ^ (row & 7)) << 4)) = va;
            bf16x8 vb = *reinterpret_cast<const bf16x8*>(Bw + (size_t)(nt * 128 + row) * 1024 + kc * 64 + slot * 8);
            *reinterpret_cast<bf16x8*>((char*)Bs + row * 128 + ((slot ^ (row & 7)) << 4)) = vb;
        }
        __syncthreads();
#pragma unroll
        for (int kk = 0; kk < 2; ++kk) {
            int slotb = kk * 4 + (lane >> 4);
            bf16x8 af[4], bv[4];
#pragma unroll
            for (int mf = 0; mf < 4; ++mf) {
                int row = wm * 64 + mf * 16 + (lane & 15);
                af[mf] = *reinterpret_cast<const bf16x8*>((char*)As + row * 128 + ((slotb ^ (row & 7)) << 4));
            }
#pragma unroll
            for (int nf = 0; nf < 4; ++nf) {
                int row = wn * 64 + nf * 16 + (lane & 15);
                bv[nf] = *reinterpret_cast<const bf16x8*>((char*)Bs + row * 128 + ((slotb ^ (row & 7)) << 4));
            }
#pragma unroll
            for (int mf = 0; mf < 4; ++mf)
#pragma unroll
                for (int nf = 0; nf < 4; ++nf)
                    acc[mf][nf] = MFMA16(af[mf], bv[nf], acc[mf][nf]);
        }
    }
#pragma unroll
    for (int nf = 0; nf < 4; ++nf) {
        int n = nt * 128 + wn * 64 + nf * 16 + (lane & 15);
        float bz = bias0[n];
#pragma unroll
        for (int mf = 0; mf < 4; ++mf)
#pragma unroll
            for (int r = 0; r < 4; ++r) {
                int rg = mt * 128 + wm * 64 + mf * 16 + (lane >> 4) * 4 + r;
                X0pre[(size_t)rg * 4096 + n] = f2bf(acc[mf][nf][r] + bz);
            }
    }
}

// ---------------- persistent recurrent kernel: weights in VGPRs ----------------
struct RecParams {
    const unsigned short* X0pre;
    const unsigned short* Wh0b;
    const unsigned short* Wx1b;
    const unsigned short* Wh1b;
    const float* bx1;
    const float* bh1;
    const float* c0in;      // [2][64][1024] fp32 (input tensor)
    unsigned short* h0sw;   // [2][65536] swizzled bf16
    unsigned short* h1sw;   // [2][65536]
    float* out;             // d_out base
};

// Block roles: bid<128 -> layer0 (m=bid&1 row-half, j=bid>>1 col strip of 16)
//              bid>=128 -> layer1 (same decomposition)
// Waves: kh = wave>>2 (K-half), g = wave&3 (gate)
__global__ void __launch_bounds__(512, 2) lstm_rec(RecParams P) {
    cg::grid_group grid = cg::this_grid();
    __shared__ __align__(16) char smem[147456];   // 128K stage + 16K comb
    float* comb = (float*)(smem + 131072);        // [4 gates][2 kh][32][16] f32

    const int tid = threadIdx.x;
    const int lane = tid & 63;
    const int wave = tid >> 6;
    const int kh = wave >> 2;
    const int g = wave & 3;
    const int rl0 = lane & 15;
    const int g4 = lane >> 4;
    const int xr = rl0 & 7;
    const int bid = blockIdx.x;
    // gate-phase thread mapping
    const int rl = tid >> 4;   // 0..31 local row
    const int cl = tid & 15;   // 0..15 local col

    if (bid < 128) {
        // ================= layer 0 =================
        const int m = bid & 1;
        const int j = bid >> 1;
        const int col = 16 * j + cl;
        const int grow = 32 * m + rl;

        bf16x8 wv[16];   // Wh0 strip: 16 cols x 512 K (this wave's K-half)
        {
            const unsigned short* wp =
                P.Wh0b + (size_t)(g * 1024 + 16 * j + rl0) * 1024 + kh * 512 + g4 * 8;
#pragma unroll
            for (int i = 0; i < 16; ++i) wv[i] = *(const bf16x8*)(wp + i * 32);
        }
        float c_reg = P.c0in[grow * 1024 + col];

        for (int it = 0; it <= TT; ++it) {
            if (it < TT) {
                const int t = it;
                // prefetch X0pre gate values (consumed in epilogue)
                const unsigned short* xp = P.X0pre + ((size_t)(t * 64 + grow)) * 4096 + col;
                unsigned short xi = xp[0], xf = xp[1024], xg = xp[2048], xo = xp[3072];

                // stage this block's 32 rows of h0[t-1] (64 KB, swizzled-linear copy)
                const unsigned short* src = P.h0sw + ((t + 1) & 1) * 65536 + 32 * m * 256;
#pragma unroll
                for (int kc = 0; kc < 4; ++kc)
#pragma unroll
                    for (int q = 0; q < 2; ++q) {
                        int seg = wave * 2 + q;
                        gll16(src + kc * 16384 + seg * 512 + lane * 8,
                              smem + kc * 16384 + seg * 1024);
                    }
                __syncthreads();

                f32x4 acc0 = (f32x4){0.f, 0.f, 0.f, 0.f};
                f32x4 acc1 = (f32x4){0.f, 0.f, 0.f, 0.f};
#pragma unroll
                for (int pc = 0; pc < 2; ++pc) {
                    const int cb = (kh * 2 + pc) * 16384;
#pragma unroll
                    for (int kk = 0; kk < 8; ++kk) {
                        int off = cb + rl0 * 512 + ((((kk << 2) + g4) ^ xr) << 4);
                        bf16x8 a0 = *(const bf16x8*)(smem + off);
                        bf16x8 a1 = *(const bf16x8*)(smem + off + 8192);
                        acc0 = MFMA16(a0, wv[pc * 8 + kk], acc0);
                        acc1 = MFMA16(a1, wv[pc * 8 + kk], acc1);
                    }
                }
                // exchange partial sums
                {
                    int cbase = (g * 2 + kh) * 512 + (g4 * 4) * 16 + rl0;
#pragma unroll
                    for (int r = 0; r < 4; ++r) {
                        comb[cbase + r * 16] = acc0[r];
                        comb[cbase + 256 + r * 16] = acc1[r];
                    }
                }
                __syncthreads();
                // gates
                {
                    int e = rl * 16 + cl;
                    float iv = comb[e] + comb[512 + e] + bf2f(xi);
                    float fv = comb[1024 + e] + comb[1536 + e] + bf2f(xf);
                    float gv = comb[2048 + e] + comb[2560 + e] + bf2f(xg);
                    float ov = comb[3072 + e] + comb[3584 + e] + bf2f(xo);
                    iv = sigm(iv); fv = sigm(fv); ov = sigm(ov); gv = tanh_f(gv);
                    float cn = fv * c_reg + iv * gv;
                    float hn = ov * tanh_f(cn);
                    c_reg = cn;
                    int s = ((col & 255) >> 3) ^ (grow & 7);
                    P.h0sw[(t & 1) * 65536 + ((col >> 8) * 64 + grow) * 256 + s * 8 + (col & 7)] = f2bf(hn);
                    if (t == TT - 1) {
                        P.out[16777216 + grow * 1024 + col] = hn;            // h_f layer0
                        P.out[16777216 + 131072 + grow * 1024 + col] = cn;   // c_f layer0
                    }
                }
            }
            __threadfence();
            grid.sync();
        }
    } else {
        // ================= layer 1 =================
        const int lb = bid - 128;
        const int m = lb & 1;
        const int j = lb >> 1;
        const int col = 16 * j + cl;
        const int grow = 32 * m + rl;

        bf16x8 wv[32];   // kh=0: Wx1 (vs h0_t), kh=1: Wh1 (vs h1_{t-1}); 16 cols x 1024 K
        {
            const unsigned short* W = kh ? P.Wh1b : P.Wx1b;
            const unsigned short* wp = W + (size_t)(g * 1024 + 16 * j + rl0) * 1024 + g4 * 8;
#pragma unroll
            for (int i = 0; i < 32; ++i) wv[i] = *(const bf16x8*)(wp + i * 32);
        }
        float c_reg = P.c0in[65536 + grow * 1024 + col];
        float b_i = P.bx1[col] + P.bh1[col];
        float b_f = P.bx1[1024 + col] + P.bh1[1024 + col];
        float b_g = P.bx1[2048 + col] + P.bh1[2048 + col];
        float b_o = P.bx1[3072 + col] + P.bh1[3072 + col];

        for (int it = 0; it <= TT; ++it) {
            if (it >= 1) {
                const int t = it - 1;
                const unsigned short* srcA = P.h0sw + (t & 1) * 65536 + 32 * m * 256;        // h0_t
                const unsigned short* srcB = P.h1sw + ((t + 1) & 1) * 65536 + 32 * m * 256;  // h1_{t-1}
#pragma unroll
                for (int kc = 0; kc < 4; ++kc)
#pragma unroll
                    for (int q = 0; q < 2; ++q) {
                        int seg = wave * 2 + q;
                        gll16(srcA + kc * 16384 + seg * 512 + lane * 8,
                              smem + kc * 16384 + seg * 1024);
                        gll16(srcB + kc * 16384 + seg * 512 + lane * 8,
                              smem + 65536 + kc * 16384 + seg * 1024);
                    }
                __syncthreads();

                f32x4 acc0 = (f32x4){0.f, 0.f, 0.f, 0.f};
                f32x4 acc1 = (f32x4){0.f, 0.f, 0.f, 0.f};
                const int regionOff = kh * 65536;
#pragma unroll
                for (int cc = 0; cc < 4; ++cc) {
                    const int cb = regionOff + cc * 16384;
#pragma unroll
                    for (int kk = 0; kk < 8; ++kk) {
                        int off = cb + rl0 * 512 + ((((kk << 2) + g4) ^ xr) << 4);
                        bf16x8 a0 = *(const bf16x8*)(smem + off);
                        bf16x8 a1 = *(const bf16x8*)(smem + off + 8192);
                        acc0 = MFMA16(a0, wv[cc * 8 + kk], acc0);
                        acc1 = MFMA16(a1, wv[cc * 8 + kk], acc1);
                    }
                }
                {
                    int cbase = (g * 2 + kh) * 512 + (g4 * 4) * 16 + rl0;
#pragma unroll
                    for (int r = 0; r < 4; ++r) {
                        comb[cbase + r * 16] = acc0[r];
                        comb[cbase + 256 + r * 16] = acc1[r];
                    }
                }
                __syncthreads();
                {
                    int e = rl * 16 + cl;
                    float iv = comb[e] + comb[512 + e] + b_i;
                    float fv = comb[1024 + e] + comb[1536 + e] + b_f;
                    float gv = comb[2048 + e] + comb[2560 + e] + b_g;
                    float ov = comb[3072 + e] + comb[3584 + e] + b_o;
                    iv = sigm(iv); fv = sigm(fv); ov = sigm(ov); gv = tanh_f(gv);
                    float cn = fv * c_reg + iv * gv;
                    float hn = ov * tanh_f(cn);
                    c_reg = cn;
                    int s = ((col & 255) >> 3) ^ (grow & 7);
                    P.h1sw[(t & 1) * 65536 + ((col >> 8) * 64 + grow) * 256 + s * 8 + (col & 7)] = f2bf(hn);
                    P.out[((size_t)grow * 256 + t) * 1024 + col] = hn;       // outputs[b][t][h]
                    if (t == TT - 1) {
                        P.out[16777216 + 65536 + grow * 1024 + col] = hn;            // h_f layer1
                        P.out[16777216 + 196608 + grow * 1024 + col] = cn;           // c_f layer1
                    }
                }
            }
            __threadfence();
            grid.sync();
        }
    }
}

// ---------------- host ----------------
extern "C" void kernel_launch(void* const* d_in, const int* in_sizes, int n_in,
                              void* d_out, int out_size, void* d_ws, size_t ws_size,
                              hipStream_t stream) {
    const float* inputs = (const float*)d_in[0];
    const float* h0in = (const float*)d_in[1];
    const float* c0in = (const float*)d_in[2];
    const float* Wx0 = (const float*)d_in[3];
    const float* bx0 = (const float*)d_in[4];
    const float* Wh0 = (const float*)d_in[5];
    const float* bh0 = (const float*)d_in[6];
    const float* Wx1 = (const float*)d_in[7];
    const float* bx1 = (const float*)d_in[8];
    const float* Wh1 = (const float*)d_in[9];
    const float* bh1 = (const float*)d_in[10];
    float* out = (float*)d_out;

    char* ws = (char*)d_ws;
    unsigned short* Wh0b = (unsigned short*)(ws + ((size_t)0 << 20));
    unsigned short* Wx1b = (unsigned short*)(ws + ((size_t)8 << 20));
    unsigned short* Wh1b = (unsigned short*)(ws + ((size_t)16 << 20));
    unsigned short* Wx0b = (unsigned short*)(ws + ((size_t)24 << 20));
    unsigned short* inbf = (unsigned short*)(ws + ((size_t)32 << 20));
    unsigned short* X0pre = (unsigned short*)(ws + ((size_t)64 << 20));
    float* bias0 = (float*)(ws + ((size_t)192 << 20));
    unsigned short* h0sw = (unsigned short*)(ws + ((size_t)192 << 20) + 16384);
    unsigned short* h1sw = h0sw + 131072;

    prep_kernel<<<2048, 256, 0, stream>>>(inputs, h0in, Wx0, bx0, Wh0, bh0, Wx1, Wh1,
                                          Wx0b, Wh0b, Wx1b, Wh1b, inbf, bias0, h0sw, h1sw);

    gemm0_kernel<<<4096, 256, 0, stream>>>(inbf, Wx0b, bias0, X0pre);

    RecParams P;
    P.X0pre = X0pre; P.Wh0b = Wh0b; P.Wx1b = Wx1b; P.Wh1b = Wh1b;
    P.bx1 = bx1; P.bh1 = bh1; P.c0in = c0in;
    P.h0sw = h0sw; P.h1sw = h1sw; P.out = out;
    void* kargs[] = { &P };
    hipLaunchCooperativeKernel((const void*)lstm_rec, dim3(NB), dim3(NT), kargs, 0, stream);
}

// Round 4
// 7058.363 us; speedup vs baseline: 2.8385x; 2.8385x over previous
//
#include <hip/hip_runtime.h>
#include <hip/hip_bf16.h>

typedef __attribute__((ext_vector_type(8))) short bf16x8;
typedef __attribute__((ext_vector_type(4))) float f32x4;

#define TT 256
#define BB 64
#define HH 1024

static constexpr int NB = 256;   // 128 layer-0 blocks + 128 layer-1 blocks
static constexpr int NT = 512;   // 8 waves per block

__device__ __forceinline__ unsigned short f2bf(float f) {
    unsigned int u = __float_as_uint(f);
    u += 0x7fffu + ((u >> 16) & 1u);   // round-to-nearest-even
    return (unsigned short)(u >> 16);
}
__device__ __forceinline__ float bf2f(unsigned short s) {
    return __uint_as_float(((unsigned int)s) << 16);
}
__device__ __forceinline__ float sigm(float x) { return 1.0f / (1.0f + __expf(-x)); }
__device__ __forceinline__ float tanh_f(float x) {
    float e = __expf(-2.0f * fabsf(x));
    return copysignf((1.0f - e) / (1.0f + e), x);
}

#define MFMA16(a, b, c) __builtin_amdgcn_mfma_f32_16x16x32_bf16((a), (b), (c), 0, 0, 0)

// async global -> LDS, 16B per lane, linear (dest = uniform base + lane*16)
__device__ __forceinline__ void gll16(const void* g, void* l) {
    __builtin_amdgcn_global_load_lds(
        (const __attribute__((address_space(1))) unsigned int*)g,
        (__attribute__((address_space(3))) unsigned int*)l,
        16, 0, 0);
}

// ---------------- prep: bf16 conversions, bias folding, swizzled h-state init, flag zeroing ----
// swizzled h layout (per 64x1024 state): ushort index = ((k>>8)*64 + b)*256 + (((k&255)>>3 ^ (b&7))<<3) + (k&7)
__global__ void __launch_bounds__(256) prep_kernel(
    const float* __restrict__ inputs, const float* __restrict__ h0in,
    const float* __restrict__ Wx0, const float* __restrict__ bx0,
    const float* __restrict__ Wh0, const float* __restrict__ bh0,
    const float* __restrict__ Wx1, const float* __restrict__ Wh1,
    unsigned short* __restrict__ Wx0b, unsigned short* __restrict__ Wh0b,
    unsigned short* __restrict__ Wx1b, unsigned short* __restrict__ Wh1b,
    unsigned short* __restrict__ inbf, float* __restrict__ bias0,
    unsigned short* __restrict__ h0sw, unsigned short* __restrict__ h1sw,
    int* __restrict__ flags)
{
    const long long Nw  = 4194304;   // 4096*1024
    const long long Nin = 16777216;  // 64*256*1024
    const long long total = 4 * Nw + Nin + 4096 + 131072 + 4096;
    for (long long idx = (long long)blockIdx.x * blockDim.x + threadIdx.x; idx < total;
         idx += (long long)gridDim.x * blockDim.x) {
        if (idx < Nw) {
            Wx0b[idx] = f2bf(Wx0[idx]);
        } else if (idx < 2 * Nw) {
            long long i = idx - Nw;      Wh0b[i] = f2bf(Wh0[i]);
        } else if (idx < 3 * Nw) {
            long long i = idx - 2 * Nw;  Wx1b[i] = f2bf(Wx1[i]);
        } else if (idx < 4 * Nw) {
            long long i = idx - 3 * Nw;  Wh1b[i] = f2bf(Wh1[i]);
        } else if (idx < 4 * Nw + Nin) {
            long long i = idx - 4 * Nw;
            int k = (int)(i & 1023);
            int t = (int)((i >> 10) & 255);
            int b = (int)(i >> 18);
            inbf[((long long)(t * 64 + b) << 10) + k] = f2bf(inputs[i]);
        } else if (idx < 4 * Nw + Nin + 4096) {
            int i = (int)(idx - (4 * Nw + Nin));
            bias0[i] = bx0[i] + bh0[i];
        } else if (idx < 4 * Nw + Nin + 4096 + 131072) {
            int i = (int)(idx - (4 * Nw + Nin + 4096));   // 0..131071
            int l = i >> 16;
            int b = (i >> 10) & 63;
            int k = i & 1023;
            unsigned short v = f2bf(h0in[i]);
            unsigned short* dst = l ? h1sw : h0sw;
            // init buffer parity 3 (= state at t = -1, 4-deep buffering)
            dst[196608 + ((k >> 8) * 64 + b) * 256 + ((((k & 255) >> 3) ^ (b & 7)) << 3) + (k & 7)] = v;
        } else {
            int i = (int)(idx - (4 * Nw + Nin + 4096 + 131072));  // 0..4095
            flags[i] = 0;
        }
    }
}

// ---------------- GEMM0: X0pre[t*64+b][n] = inputs@Wx0^T + bias0, bf16 out ----------------
__global__ void __launch_bounds__(256) gemm0_kernel(
    const unsigned short* __restrict__ A,   // [16384][1024] bf16, row = t*64+b
    const unsigned short* __restrict__ Bw,  // [4096][1024] bf16
    const float* __restrict__ bias0,
    unsigned short* __restrict__ X0pre)     // [16384][4096] bf16
{
    __shared__ __align__(16) char smem[32768];
    unsigned short* As = (unsigned short*)smem;            // [128][64] swizzled
    unsigned short* Bs = (unsigned short*)(smem + 16384);  // [128][64] swizzled
    const int tid = threadIdx.x, lane = tid & 63, wave = tid >> 6;
    const int wm = wave >> 1, wn = wave & 1;
    const int mt = blockIdx.x >> 5, nt = blockIdx.x & 31;

    f32x4 acc[4][4];
#pragma unroll
    for (int a = 0; a < 4; ++a)
#pragma unroll
        for (int b = 0; b < 4; ++b) acc[a][b] = (f32x4){0.f, 0.f, 0.f, 0.f};

    for (int kc = 0; kc < 16; ++kc) {
        __syncthreads();
#pragma unroll
        for (int p = 0; p < 4; ++p) {
            int cidx = tid + p * 256;
            int row = cidx >> 3, slot = cidx & 7;
            bf16x8 va = *reinterpret_cast<const bf16x8*>(A + (size_t)(mt * 128 + row) * 1024 + kc * 64 + slot * 8);
            *reinterpret_cast<bf16x8*>((char*)As + row * 128 + ((slot ^ (row & 7)) << 4)) = va;
            bf16x8 vb = *reinterpret_cast<const bf16x8*>(Bw + (size_t)(nt * 128 + row) * 1024 + kc * 64 + slot * 8);
            *reinterpret_cast<bf16x8*>((char*)Bs + row * 128 + ((slot ^ (row & 7)) << 4)) = vb;
        }
        __syncthreads();
#pragma unroll
        for (int kk = 0; kk < 2; ++kk) {
            int slotb = kk * 4 + (lane >> 4);
            bf16x8 af[4], bv[4];
#pragma unroll
            for (int mf = 0; mf < 4; ++mf) {
                int row = wm * 64 + mf * 16 + (lane & 15);
                af[mf] = *reinterpret_cast<const bf16x8*>((char*)As + row * 128 + ((slotb ^ (row & 7)) << 4));
            }
#pragma unroll
            for (int nf = 0; nf < 4; ++nf) {
                int row = wn * 64 + nf * 16 + (lane & 15);
                bv[nf] = *reinterpret_cast<const bf16x8*>((char*)Bs + row * 128 + ((slotb ^ (row & 7)) << 4));
            }
#pragma unroll
            for (int mf = 0; mf < 4; ++mf)
#pragma unroll
                for (int nf = 0; nf < 4; ++nf)
                    acc[mf][nf] = MFMA16(af[mf], bv[nf], acc[mf][nf]);
        }
    }
#pragma unroll
    for (int nf = 0; nf < 4; ++nf) {
        int n = nt * 128 + wn * 64 + nf * 16 + (lane & 15);
        float bz = bias0[n];
#pragma unroll
        for (int mf = 0; mf < 4; ++mf)
#pragma unroll
            for (int r = 0; r < 4; ++r) {
                int rg = mt * 128 + wm * 64 + mf * 16 + (lane >> 4) * 4 + r;
                X0pre[(size_t)rg * 4096 + n] = f2bf(acc[mf][nf][r] + bz);
            }
    }
}

// ---------------- persistent recurrent kernel: weights in VGPRs, flag-based sync ----------------
struct RecParams {
    const unsigned short* X0pre;
    const unsigned short* Wh0b;
    const unsigned short* Wx1b;
    const unsigned short* Wh1b;
    const float* bx1;
    const float* bh1;
    const float* c0in;      // [2][64][1024] fp32 (input tensor)
    unsigned short* h0sw;   // [4][65536] swizzled bf16 (4-deep ring)
    unsigned short* h1sw;   // [4][65536]
    int* flags;             // [4 groups][64 blocks] stride 16 ints (64B)
    float* out;             // d_out base
};

// flags group id: (layer*2 + m)*64 + j ; flag value = last completed step + 1
// Block roles: bid<128 -> layer0 (m=bid&1, j=bid>>1), bid>=128 -> layer1 (same decomposition)
// Waves: kh = wave>>2 (K-half), g = wave&3 (gate)
__global__ void __launch_bounds__(512, 2) lstm_rec(RecParams P) {
    __shared__ __align__(16) char smem[147456];   // 128K stage + 16K comb
    float* comb = (float*)(smem + 131072);        // [4 gates][2 kh][32][16] f32

    const int tid = threadIdx.x;
    const int lane = tid & 63;
    const int wave = tid >> 6;
    const int kh = wave >> 2;
    const int g = wave & 3;
    const int rl0 = lane & 15;
    const int g4 = lane >> 4;
    const int xr = rl0 & 7;
    const int bid = blockIdx.x;
    const int rl = tid >> 4;   // 0..31 local row
    const int cl = tid & 15;   // 0..15 local col
    int* flags = P.flags;

    if (bid < 128) {
        // ================= layer 0 =================
        const int m = bid & 1;
        const int j = bid >> 1;
        const int col = 16 * j + cl;
        const int grow = 32 * m + rl;
        const int pbase = m * 64;        // own group (layer0, m)
        const int sbase = (2 + m) * 64;  // layer1, m
        const int myslot = (m * 64 + j) * 16;

        bf16x8 wv[16];   // Wh0 strip: 16 cols x 512 K (this wave's K-half)
        {
            const unsigned short* wp =
                P.Wh0b + (size_t)(g * 1024 + 16 * j + rl0) * 1024 + kh * 512 + g4 * 8;
#pragma unroll
            for (int i = 0; i < 16; ++i) wv[i] = *(const bf16x8*)(wp + i * 32);
        }
        float c_reg = P.c0in[grow * 1024 + col];

        for (int t = 0; t < TT; ++t) {
            // X0pre prefetch: read-only, issue before the wait so latency hides under polling
            const unsigned short* xp = P.X0pre + ((size_t)(t * 64 + grow)) * 4096 + col;
            unsigned short xi = xp[0], xf = xp[1024], xg = xp[2048], xo = xp[3072];

            // wait: own group >= t (h0[t-1] ready), layer1 group >= t-3 (4-deep ring safety)
            if (t > 0) {
                const int tgt2 = t - 3;
                int ok;
                do {
                    int v = 1;
                    if (tid < 64)
                        v = (__hip_atomic_load(flags + (pbase + tid) * 16,
                                               __ATOMIC_RELAXED, __HIP_MEMORY_SCOPE_AGENT) >= t);
                    else if (tid < 128 && tgt2 > 0)
                        v = (__hip_atomic_load(flags + (sbase + (tid - 64)) * 16,
                                               __ATOMIC_RELAXED, __HIP_MEMORY_SCOPE_AGENT) >= tgt2);
                    ok = __syncthreads_and(v);
                } while (!ok);
                __builtin_amdgcn_fence(__ATOMIC_ACQUIRE, "agent");
            } else {
                __syncthreads();
            }

            // stage this block's 32 rows of h0[t-1] (64 KB, swizzled-linear copy)
            const unsigned short* src = P.h0sw + (size_t)((t + 3) & 3) * 65536 + 32 * m * 256;
#pragma unroll
            for (int kc = 0; kc < 4; ++kc)
#pragma unroll
                for (int q = 0; q < 2; ++q) {
                    int seg = wave * 2 + q;
                    gll16(src + kc * 16384 + seg * 512 + lane * 8,
                          smem + kc * 16384 + seg * 1024);
                }
            __syncthreads();

            f32x4 acc0 = (f32x4){0.f, 0.f, 0.f, 0.f};
            f32x4 acc1 = (f32x4){0.f, 0.f, 0.f, 0.f};
#pragma unroll
            for (int pc = 0; pc < 2; ++pc) {
                const int cb = (kh * 2 + pc) * 16384;
#pragma unroll
                for (int kk = 0; kk < 8; ++kk) {
                    int off = cb + rl0 * 512 + ((((kk << 2) + g4) ^ xr) << 4);
                    bf16x8 a0 = *(const bf16x8*)(smem + off);
                    bf16x8 a1 = *(const bf16x8*)(smem + off + 8192);
                    acc0 = MFMA16(a0, wv[pc * 8 + kk], acc0);
                    acc1 = MFMA16(a1, wv[pc * 8 + kk], acc1);
                }
            }
            // exchange partial sums
            {
                int cbase = (g * 2 + kh) * 512 + (g4 * 4) * 16 + rl0;
#pragma unroll
                for (int r = 0; r < 4; ++r) {
                    comb[cbase + r * 16] = acc0[r];
                    comb[cbase + 256 + r * 16] = acc1[r];
                }
            }
            __syncthreads();
            // gates
            {
                int e = rl * 16 + cl;
                float iv = comb[e] + comb[512 + e] + bf2f(xi);
                float fv = comb[1024 + e] + comb[1536 + e] + bf2f(xf);
                float gv = comb[2048 + e] + comb[2560 + e] + bf2f(xg);
                float ov = comb[3072 + e] + comb[3584 + e] + bf2f(xo);
                iv = sigm(iv); fv = sigm(fv); ov = sigm(ov); gv = tanh_f(gv);
                float cn = fv * c_reg + iv * gv;
                float hn = ov * tanh_f(cn);
                c_reg = cn;
                int s = ((col & 255) >> 3) ^ (grow & 7);
                P.h0sw[(size_t)(t & 3) * 65536 + ((col >> 8) * 64 + grow) * 256 + s * 8 + (col & 7)] = f2bf(hn);
                if (t == TT - 1) {
                    P.out[16777216 + grow * 1024 + col] = hn;            // h_f layer0
                    P.out[16777216 + 131072 + grow * 1024 + col] = cn;   // c_f layer0
                }
            }
            __syncthreads();
            if (tid == 0)
                __hip_atomic_store(flags + myslot, t + 1,
                                   __ATOMIC_RELEASE, __HIP_MEMORY_SCOPE_AGENT);
        }
    } else {
        // ================= layer 1 =================
        const int lb = bid - 128;
        const int m = lb & 1;
        const int j = lb >> 1;
        const int col = 16 * j + cl;
        const int grow = 32 * m + rl;
        const int pbase = m * 64;        // layer0, m
        const int sbase = (2 + m) * 64;  // own group (layer1, m)
        const int myslot = ((2 + m) * 64 + j) * 16;

        bf16x8 wv[32];   // kh=0: Wx1 (vs h0_t), kh=1: Wh1 (vs h1_{t-1}); 16 cols x 1024 K
        {
            const unsigned short* W = kh ? P.Wh1b : P.Wx1b;
            const unsigned short* wp = W + (size_t)(g * 1024 + 16 * j + rl0) * 1024 + g4 * 8;
#pragma unroll
            for (int i = 0; i < 32; ++i) wv[i] = *(const bf16x8*)(wp + i * 32);
        }
        float c_reg = P.c0in[65536 + grow * 1024 + col];
        float b_i = P.bx1[col] + P.bh1[col];
        float b_f = P.bx1[1024 + col] + P.bh1[1024 + col];
        float b_g = P.bx1[2048 + col] + P.bh1[2048 + col];
        float b_o = P.bx1[3072 + col] + P.bh1[3072 + col];

        for (int t = 0; t < TT; ++t) {
            // wait: layer0 >= t+1 (h0[t] ready), own group >= t (h1[t-1] ready)
            {
                int ok;
                do {
                    int v = 1;
                    if (tid < 64)
                        v = (__hip_atomic_load(flags + (pbase + tid) * 16,
                                               __ATOMIC_RELAXED, __HIP_MEMORY_SCOPE_AGENT) >= t + 1);
                    else if (tid < 128 && t > 0)
                        v = (__hip_atomic_load(flags + (sbase + (tid - 64)) * 16,
                                               __ATOMIC_RELAXED, __HIP_MEMORY_SCOPE_AGENT) >= t);
                    ok = __syncthreads_and(v);
                } while (!ok);
                __builtin_amdgcn_fence(__ATOMIC_ACQUIRE, "agent");
            }

            const unsigned short* srcA = P.h0sw + (size_t)(t & 3) * 65536 + 32 * m * 256;        // h0_t
            const unsigned short* srcB = P.h1sw + (size_t)((t + 3) & 3) * 65536 + 32 * m * 256;  // h1_{t-1}
#pragma unroll
            for (int kc = 0; kc < 4; ++kc)
#pragma unroll
                for (int q = 0; q < 2; ++q) {
                    int seg = wave * 2 + q;
                    gll16(srcA + kc * 16384 + seg * 512 + lane * 8,
                          smem + kc * 16384 + seg * 1024);
                    gll16(srcB + kc * 16384 + seg * 512 + lane * 8,
                          smem + 65536 + kc * 16384 + seg * 1024);
                }
            __syncthreads();

            f32x4 acc0 = (f32x4){0.f, 0.f, 0.f, 0.f};
            f32x4 acc1 = (f32x4){0.f, 0.f, 0.f, 0.f};
            const int regionOff = kh * 65536;
#pragma unroll
            for (int cc = 0; cc < 4; ++cc) {
                const int cb = regionOff + cc * 16384;
#pragma unroll
                for (int kk = 0; kk < 8; ++kk) {
                    int off = cb + rl0 * 512 + ((((kk << 2) + g4) ^ xr) << 4);
                    bf16x8 a0 = *(const bf16x8*)(smem + off);
                    bf16x8 a1 = *(const bf16x8*)(smem + off + 8192);
                    acc0 = MFMA16(a0, wv[cc * 8 + kk], acc0);
                    acc1 = MFMA16(a1, wv[cc * 8 + kk], acc1);
                }
            }
            {
                int cbase = (g * 2 + kh) * 512 + (g4 * 4) * 16 + rl0;
#pragma unroll
                for (int r = 0; r < 4; ++r) {
                    comb[cbase + r * 16] = acc0[r];
                    comb[cbase + 256 + r * 16] = acc1[r];
                }
            }
            __syncthreads();
            {
                int e = rl * 16 + cl;
                float iv = comb[e] + comb[512 + e] + b_i;
                float fv = comb[1024 + e] + comb[1536 + e] + b_f;
                float gv = comb[2048 + e] + comb[2560 + e] + b_g;
                float ov = comb[3072 + e] + comb[3584 + e] + b_o;
                iv = sigm(iv); fv = sigm(fv); ov = sigm(ov); gv = tanh_f(gv);
                float cn = fv * c_reg + iv * gv;
                float hn = ov * tanh_f(cn);
                c_reg = cn;
                int s = ((col & 255) >> 3) ^ (grow & 7);
                P.h1sw[(size_t)(t & 3) * 65536 + ((col >> 8) * 64 + grow) * 256 + s * 8 + (col & 7)] = f2bf(hn);
                P.out[((size_t)grow * 256 + t) * 1024 + col] = hn;       // outputs[b][t][h]
                if (t == TT - 1) {
                    P.out[16777216 + 65536 + grow * 1024 + col] = hn;    // h_f layer1
                    P.out[16777216 + 196608 + grow * 1024 + col] = cn;   // c_f layer1
                }
            }
            __syncthreads();
            if (tid == 0)
                __hip_atomic_store(flags + myslot, t + 1,
                                   __ATOMIC_RELEASE, __HIP_MEMORY_SCOPE_AGENT);
        }
    }
}

// ---------------- host ----------------
extern "C" void kernel_launch(void* const* d_in, const int* in_sizes, int n_in,
                              void* d_out, int out_size, void* d_ws, size_t ws_size,
                              hipStream_t stream) {
    const float* inputs = (const float*)d_in[0];
    const float* h0in = (const float*)d_in[1];
    const float* c0in = (const float*)d_in[2];
    const float* Wx0 = (const float*)d_in[3];
    const float* bx0 = (const float*)d_in[4];
    const float* Wh0 = (const float*)d_in[5];
    const float* bh0 = (const float*)d_in[6];
    const float* Wx1 = (const float*)d_in[7];
    const float* bx1 = (const float*)d_in[8];
    const float* Wh1 = (const float*)d_in[9];
    const float* bh1 = (const float*)d_in[10];
    float* out = (float*)d_out;

    char* ws = (char*)d_ws;
    unsigned short* Wh0b = (unsigned short*)(ws + ((size_t)0 << 20));
    unsigned short* Wx1b = (unsigned short*)(ws + ((size_t)8 << 20));
    unsigned short* Wh1b = (unsigned short*)(ws + ((size_t)16 << 20));
    unsigned short* Wx0b = (unsigned short*)(ws + ((size_t)24 << 20));
    unsigned short* inbf = (unsigned short*)(ws + ((size_t)32 << 20));
    unsigned short* X0pre = (unsigned short*)(ws + ((size_t)64 << 20));
    float* bias0 = (float*)(ws + ((size_t)192 << 20));
    unsigned short* h0sw = (unsigned short*)(ws + ((size_t)192 << 20) + 16384);   // 4*65536 ushorts
    unsigned short* h1sw = h0sw + 262144;
    int* flags = (int*)(h1sw + 262144);                                           // 4096 ints

    prep_kernel<<<2048, 256, 0, stream>>>(inputs, h0in, Wx0, bx0, Wh0, bh0, Wx1, Wh1,
                                          Wx0b, Wh0b, Wx1b, Wh1b, inbf, bias0, h0sw, h1sw, flags);

    gemm0_kernel<<<4096, 256, 0, stream>>>(inbf, Wx0b, bias0, X0pre);

    RecParams P;
    P.X0pre = X0pre; P.Wh0b = Wh0b; P.Wx1b = Wx1b; P.Wh1b = Wh1b;
    P.bx1 = bx1; P.bh1 = bh1; P.c0in = c0in;
    P.h0sw = h0sw; P.h1sw = h1sw; P.flags = flags; P.out = out;
    void* kargs[] = { &P };
    hipLaunchCooperativeKernel((const void*)lstm_rec, dim3(NB), dim3(NT), kargs, 0, stream);
}

// Round 5
// 1813.016 us; speedup vs baseline: 11.0507x; 3.8932x over previous
//
#include <hip/hip_runtime.h>
#include <hip/hip_bf16.h>

typedef __attribute__((ext_vector_type(8))) short bf16x8;
typedef __attribute__((ext_vector_type(4))) float f32x4;

#define TT 256
#define BB 64
#define HH 1024

static constexpr int NB = 256;   // 128 layer-0 blocks + 128 layer-1 blocks
static constexpr int NT = 512;   // 8 waves per block

__device__ __forceinline__ unsigned short f2bf(float f) {
    unsigned int u = __float_as_uint(f);
    u += 0x7fffu + ((u >> 16) & 1u);   // round-to-nearest-even
    return (unsigned short)(u >> 16);
}
__device__ __forceinline__ float bf2f(unsigned short s) {
    return __uint_as_float(((unsigned int)s) << 16);
}
__device__ __forceinline__ float sigm(float x) { return 1.0f / (1.0f + __expf(-x)); }
__device__ __forceinline__ float tanh_f(float x) {
    float e = __expf(-2.0f * fabsf(x));
    return copysignf((1.0f - e) / (1.0f + e), x);
}

#define MFMA16(a, b, c) __builtin_amdgcn_mfma_f32_16x16x32_bf16((a), (b), (c), 0, 0, 0)

// async global -> LDS, 16B/lane, device-coherent (sc0|sc1 = CPol GLC|SCC = 17):
// bypasses (potentially stale) L1/L2 so no acquire-fence/cache-invalidate is needed.
__device__ __forceinline__ void gll16c(const void* g, void* l) {
    __builtin_amdgcn_global_load_lds(
        (const __attribute__((address_space(1))) unsigned int*)g,
        (__attribute__((address_space(3))) unsigned int*)l,
        16, 0, 17);
}
// device-coherent flag load (fresh from IF$/memory)
__device__ __forceinline__ int ldg_i32_sc(const int* p) {
    int r;
    asm volatile("global_load_dword %0, %1, off sc0 sc1\n\ts_waitcnt vmcnt(0)"
                 : "=v"(r) : "v"(p) : "memory");
    return r;
}
// write-through h-state store (visible device-wide once vmcnt retires)
__device__ __forceinline__ void stg_u16_sc(unsigned short* p, unsigned int v) {
    asm volatile("global_store_short %0, %1, off sc0 sc1" :: "v"(p), "v"(v) : "memory");
}
// release-ish flag store: own prior stores already drained (pre-barrier waitcnt)
__device__ __forceinline__ void st_flag_sc(int* p, int v) {
    asm volatile("s_waitcnt vmcnt(0)\n\tglobal_store_dword %0, %1, off sc0 sc1"
                 :: "v"(p), "v"(v) : "memory");
}

// ---------------- prep: bf16 conversions, bias folding, swizzled h-state init, flag zeroing ----
// swizzled h layout (per 64x1024 state): ushort index = ((k>>8)*64 + b)*256 + (((k&255)>>3 ^ (b&7))<<3) + (k&7)
__global__ void __launch_bounds__(256) prep_kernel(
    const float* __restrict__ inputs, const float* __restrict__ h0in,
    const float* __restrict__ Wx0, const float* __restrict__ bx0,
    const float* __restrict__ Wh0, const float* __restrict__ bh0,
    const float* __restrict__ Wx1, const float* __restrict__ Wh1,
    unsigned short* __restrict__ Wx0b, unsigned short* __restrict__ Wh0b,
    unsigned short* __restrict__ Wx1b, unsigned short* __restrict__ Wh1b,
    unsigned short* __restrict__ inbf, float* __restrict__ bias0,
    unsigned short* __restrict__ h0sw, unsigned short* __restrict__ h1sw,
    int* __restrict__ flags)
{
    const long long Nw  = 4194304;   // 4096*1024
    const long long Nin = 16777216;  // 64*256*1024
    const long long total = 4 * Nw + Nin + 4096 + 131072 + 4096;
    for (long long idx = (long long)blockIdx.x * blockDim.x + threadIdx.x; idx < total;
         idx += (long long)gridDim.x * blockDim.x) {
        if (idx < Nw) {
            Wx0b[idx] = f2bf(Wx0[idx]);
        } else if (idx < 2 * Nw) {
            long long i = idx - Nw;      Wh0b[i] = f2bf(Wh0[i]);
        } else if (idx < 3 * Nw) {
            long long i = idx - 2 * Nw;  Wx1b[i] = f2bf(Wx1[i]);
        } else if (idx < 4 * Nw) {
            long long i = idx - 3 * Nw;  Wh1b[i] = f2bf(Wh1[i]);
        } else if (idx < 4 * Nw + Nin) {
            long long i = idx - 4 * Nw;
            int k = (int)(i & 1023);
            int t = (int)((i >> 10) & 255);
            int b = (int)(i >> 18);
            inbf[((long long)(t * 64 + b) << 10) + k] = f2bf(inputs[i]);
        } else if (idx < 4 * Nw + Nin + 4096) {
            int i = (int)(idx - (4 * Nw + Nin));
            bias0[i] = bx0[i] + bh0[i];
        } else if (idx < 4 * Nw + Nin + 4096 + 131072) {
            int i = (int)(idx - (4 * Nw + Nin + 4096));   // 0..131071
            int l = i >> 16;
            int b = (i >> 10) & 63;
            int k = i & 1023;
            unsigned short v = f2bf(h0in[i]);
            unsigned short* dst = l ? h1sw : h0sw;
            // init ring slot 3 (= state at t = -1, 4-deep buffering)
            dst[196608 + ((k >> 8) * 64 + b) * 256 + ((((k & 255) >> 3) ^ (b & 7)) << 3) + (k & 7)] = v;
        } else {
            int i = (int)(idx - (4 * Nw + Nin + 4096 + 131072));  // 0..4095
            flags[i] = 0;
        }
    }
}

// ---------------- GEMM0: X0pre[t*64+b][n] = inputs@Wx0^T + bias0, bf16 out ----------------
__global__ void __launch_bounds__(256) gemm0_kernel(
    const unsigned short* __restrict__ A,   // [16384][1024] bf16, row = t*64+b
    const unsigned short* __restrict__ Bw,  // [4096][1024] bf16
    const float* __restrict__ bias0,
    unsigned short* __restrict__ X0pre)     // [16384][4096] bf16
{
    __shared__ __align__(16) char smem[32768];
    unsigned short* As = (unsigned short*)smem;            // [128][64] swizzled
    unsigned short* Bs = (unsigned short*)(smem + 16384);  // [128][64] swizzled
    const int tid = threadIdx.x, lane = tid & 63, wave = tid >> 6;
    const int wm = wave >> 1, wn = wave & 1;
    const int mt = blockIdx.x >> 5, nt = blockIdx.x & 31;

    f32x4 acc[4][4];
#pragma unroll
    for (int a = 0; a < 4; ++a)
#pragma unroll
        for (int b = 0; b < 4; ++b) acc[a][b] = (f32x4){0.f, 0.f, 0.f, 0.f};

    for (int kc = 0; kc < 16; ++kc) {
        __syncthreads();
#pragma unroll
        for (int p = 0; p < 4; ++p) {
            int cidx = tid + p * 256;
            int row = cidx >> 3, slot = cidx & 7;
            bf16x8 va = *reinterpret_cast<const bf16x8*>(A + (size_t)(mt * 128 + row) * 1024 + kc * 64 + slot * 8);
            *reinterpret_cast<bf16x8*>((char*)As + row * 128 + ((slot ^ (row & 7)) << 4)) = va;
            bf16x8 vb = *reinterpret_cast<const bf16x8*>(Bw + (size_t)(nt * 128 + row) * 1024 + kc * 64 + slot * 8);
            *reinterpret_cast<bf16x8*>((char*)Bs + row * 128 + ((slot ^ (row & 7)) << 4)) = vb;
        }
        __syncthreads();
#pragma unroll
        for (int kk = 0; kk < 2; ++kk) {
            int slotb = kk * 4 + (lane >> 4);
            bf16x8 af[4], bv[4];
#pragma unroll
            for (int mf = 0; mf < 4; ++mf) {
                int row = wm * 64 + mf * 16 + (lane & 15);
                af[mf] = *reinterpret_cast<const bf16x8*>((char*)As + row * 128 + ((slotb ^ (row & 7)) << 4));
            }
#pragma unroll
            for (int nf = 0; nf < 4; ++nf) {
                int row = wn * 64 + nf * 16 + (lane & 15);
                bv[nf] = *reinterpret_cast<const bf16x8*>((char*)Bs + row * 128 + ((slotb ^ (row & 7)) << 4));
            }
#pragma unroll
            for (int mf = 0; mf < 4; ++mf)
#pragma unroll
                for (int nf = 0; nf < 4; ++nf)
                    acc[mf][nf] = MFMA16(af[mf], bv[nf], acc[mf][nf]);
        }
    }
#pragma unroll
    for (int nf = 0; nf < 4; ++nf) {
        int n = nt * 128 + wn * 64 + nf * 16 + (lane & 15);
        float bz = bias0[n];
#pragma unroll
        for (int mf = 0; mf < 4; ++mf)
#pragma unroll
            for (int r = 0; r < 4; ++r) {
                int rg = mt * 128 + wm * 64 + mf * 16 + (lane >> 4) * 4 + r;
                X0pre[(size_t)rg * 4096 + n] = f2bf(acc[mf][nf][r] + bz);
            }
    }
}

// ---------------- persistent recurrent kernel: weights in regs, fence-free flag sync ----------------
struct RecParams {
    const unsigned short* X0pre;
    const unsigned short* Wh0b;
    const unsigned short* Wx1b;
    const unsigned short* Wh1b;
    const float* bx1;
    const float* bh1;
    const float* c0in;      // [2][64][1024] fp32 (input tensor)
    unsigned short* h0sw;   // [4][65536] swizzled bf16 (4-deep ring)
    unsigned short* h1sw;   // [4][65536]
    int* flags;             // [4 groups][64 blocks] stride 16 ints (64B)
    float* out;             // d_out base
};

// flags group id: (layer*2 + m)*64 + j ; flag value = completed steps
// Block roles: bid<128 -> layer0 (m=bid&1, j=bid>>1), bid>=128 -> layer1 (same decomposition)
// Waves: kh = wave>>2 (K-half), g = wave&3 (gate)
__global__ void __launch_bounds__(512, 2) lstm_rec(RecParams P) {
    __shared__ __align__(16) char smem[147456];   // [0,64K) h0 stage, [64K,128K) h1 stage, comb
    float* comb = (float*)(smem + 131072);        // [4 gates][2 kh][32][16] f32

    const int tid = threadIdx.x;
    const int lane = tid & 63;
    const int wave = tid >> 6;
    const int kh = wave >> 2;
    const int g = wave & 3;
    const int rl0 = lane & 15;
    const int g4 = lane >> 4;
    const int xr = rl0 & 7;
    const int bid = blockIdx.x;
    const int rl = tid >> 4;   // 0..31 local row
    const int cl = tid & 15;   // 0..15 local col
    int* flags = P.flags;

    if (bid < 128) {
        // ================= layer 0 =================
        const int m = bid & 1;
        const int j = bid >> 1;
        const int col = 16 * j + cl;
        const int grow = 32 * m + rl;
        const int pbase = m * 64;        // own group (layer0, m)
        const int sbase = (2 + m) * 64;  // layer1, m
        int* myflag = flags + (m * 64 + j) * 16;

        bf16x8 wv[16];   // Wh0 strip: 16 cols x 512 K (this wave's K-half)
        {
            const unsigned short* wp =
                P.Wh0b + (size_t)(g * 1024 + 16 * j + rl0) * 1024 + kh * 512 + g4 * 8;
#pragma unroll
            for (int i = 0; i < 16; ++i) wv[i] = *(const bf16x8*)(wp + i * 32);
        }
        float c_reg = P.c0in[grow * 1024 + col];

        for (int t = 0; t < TT; ++t) {
            // X0pre prefetch (plain cached loads; L2 stays hot — no invalidates anymore)
            const unsigned short* xp = P.X0pre + ((size_t)(t * 64 + grow)) * 4096 + col;
            unsigned short xi = xp[0], xf = xp[1024], xg = xp[2048], xo = xp[3072];

            // wave-autonomous wait: own group >= t, layer1 group >= t-3 (ring safety)
            if (t > 0) {
                const int tgt2 = t - 3;
                const int* f1 = flags + (pbase + lane) * 16;
                const int* f2 = flags + (sbase + lane) * 16;
                for (;;) {
                    int ok = (ldg_i32_sc(f1) >= t);
                    if (tgt2 > 0) ok &= (ldg_i32_sc(f2) >= tgt2);
                    if (__all(ok)) break;
                }
            }

            // stage this block's 32 rows of h0[t-1] (64 KB, coherent loads, swizzled-linear)
            const unsigned short* src = P.h0sw + (size_t)((t + 3) & 3) * 65536 + m * 8192;
#pragma unroll
            for (int kc = 0; kc < 4; ++kc)
#pragma unroll
                for (int q = 0; q < 2; ++q) {
                    int seg = wave * 2 + q;
                    gll16c(src + kc * 16384 + seg * 512 + lane * 8,
                           smem + kc * 16384 + seg * 1024);
                }
            __syncthreads();

            f32x4 acc0 = (f32x4){0.f, 0.f, 0.f, 0.f};
            f32x4 acc1 = (f32x4){0.f, 0.f, 0.f, 0.f};
#pragma unroll
            for (int pc = 0; pc < 2; ++pc) {
                const int cb = (kh * 2 + pc) * 16384;
#pragma unroll
                for (int kk = 0; kk < 8; ++kk) {
                    int off = cb + rl0 * 512 + ((((kk << 2) + g4) ^ xr) << 4);
                    bf16x8 a0 = *(const bf16x8*)(smem + off);
                    bf16x8 a1 = *(const bf16x8*)(smem + off + 8192);
                    acc0 = MFMA16(a0, wv[pc * 8 + kk], acc0);
                    acc1 = MFMA16(a1, wv[pc * 8 + kk], acc1);
                }
            }
            {
                int cbase = (g * 2 + kh) * 512 + (g4 * 4) * 16 + rl0;
#pragma unroll
                for (int r = 0; r < 4; ++r) {
                    comb[cbase + r * 16] = acc0[r];
                    comb[cbase + 256 + r * 16] = acc1[r];
                }
            }
            __syncthreads();
            // gates
            {
                int e = rl * 16 + cl;
                float iv = comb[e] + comb[512 + e] + bf2f(xi);
                float fv = comb[1024 + e] + comb[1536 + e] + bf2f(xf);
                float gv = comb[2048 + e] + comb[2560 + e] + bf2f(xg);
                float ov = comb[3072 + e] + comb[3584 + e] + bf2f(xo);
                iv = sigm(iv); fv = sigm(fv); ov = sigm(ov); gv = tanh_f(gv);
                float cn = fv * c_reg + iv * gv;
                float hn = ov * tanh_f(cn);
                c_reg = cn;
                int s = ((col & 255) >> 3) ^ (grow & 7);
                stg_u16_sc(&P.h0sw[(size_t)(t & 3) * 65536 + ((col >> 8) * 64 + grow) * 256 + s * 8 + (col & 7)],
                           (unsigned int)f2bf(hn));
                if (t == TT - 1) {
                    P.out[16777216 + grow * 1024 + col] = hn;            // h_f layer0
                    P.out[16777216 + 131072 + grow * 1024 + col] = cn;   // c_f layer0
                }
            }
            asm volatile("s_waitcnt vmcnt(0)" ::: "memory");
            __syncthreads();
            if (tid == 0) st_flag_sc(myflag, t + 1);
        }
    } else {
        // ================= layer 1 (split-phase: Wh1*h1 before h0 arrives) =================
        const int lb = bid - 128;
        const int m = lb & 1;
        const int j = lb >> 1;
        const int col = 16 * j + cl;
        const int grow = 32 * m + rl;
        const int pbase = m * 64;        // layer0, m
        const int sbase = (2 + m) * 64;  // own group (layer1, m)
        int* myflag = flags + ((2 + m) * 64 + j) * 16;

        bf16x8 wv0[16];  // Wx1 strip (vs h0_t):     16 cols x 512 K (this wave's K-half)
        bf16x8 wv1[16];  // Wh1 strip (vs h1_{t-1}): 16 cols x 512 K
        {
            const size_t woff = (size_t)(g * 1024 + 16 * j + rl0) * 1024 + kh * 512 + g4 * 8;
            const unsigned short* wp0 = P.Wx1b + woff;
            const unsigned short* wp1 = P.Wh1b + woff;
#pragma unroll
            for (int i = 0; i < 16; ++i) { wv0[i] = *(const bf16x8*)(wp0 + i * 32); wv1[i] = *(const bf16x8*)(wp1 + i * 32); }
        }
        float c_reg = P.c0in[65536 + grow * 1024 + col];
        float b_i = P.bx1[col] + P.bh1[col];
        float b_f = P.bx1[1024 + col] + P.bh1[1024 + col];
        float b_g = P.bx1[2048 + col] + P.bh1[2048 + col];
        float b_o = P.bx1[3072 + col] + P.bh1[3072 + col];

        for (int t = 0; t < TT; ++t) {
            // phase W: wait own group >= t (h1[t-1] ready), stage + accumulate Wh1 part
            if (t > 0) {
                const int* f2 = flags + (sbase + lane) * 16;
                for (;;) { if (__all(ldg_i32_sc(f2) >= t)) break; }
            }
            const unsigned short* srcB = P.h1sw + (size_t)((t + 3) & 3) * 65536 + m * 8192;
#pragma unroll
            for (int kc = 0; kc < 4; ++kc)
#pragma unroll
                for (int q = 0; q < 2; ++q) {
                    int seg = wave * 2 + q;
                    gll16c(srcB + kc * 16384 + seg * 512 + lane * 8,
                           smem + 65536 + kc * 16384 + seg * 1024);
                }
            __syncthreads();

            f32x4 acc0 = (f32x4){0.f, 0.f, 0.f, 0.f};
            f32x4 acc1 = (f32x4){0.f, 0.f, 0.f, 0.f};
#pragma unroll
            for (int pc = 0; pc < 2; ++pc) {
                const int cb = 65536 + (kh * 2 + pc) * 16384;
#pragma unroll
                for (int kk = 0; kk < 8; ++kk) {
                    int off = cb + rl0 * 512 + ((((kk << 2) + g4) ^ xr) << 4);
                    bf16x8 a0 = *(const bf16x8*)(smem + off);
                    bf16x8 a1 = *(const bf16x8*)(smem + off + 8192);
                    acc0 = MFMA16(a0, wv1[pc * 8 + kk], acc0);
                    acc1 = MFMA16(a1, wv1[pc * 8 + kk], acc1);
                }
            }

            // phase X: wait layer0 >= t+1 (h0[t] ready), stage + accumulate Wx1 part
            {
                const int* f1 = flags + (pbase + lane) * 16;
                for (;;) { if (__all(ldg_i32_sc(f1) >= t + 1)) break; }
            }
            const unsigned short* srcA = P.h0sw + (size_t)(t & 3) * 65536 + m * 8192;
#pragma unroll
            for (int kc = 0; kc < 4; ++kc)
#pragma unroll
                for (int q = 0; q < 2; ++q) {
                    int seg = wave * 2 + q;
                    gll16c(srcA + kc * 16384 + seg * 512 + lane * 8,
                           smem + kc * 16384 + seg * 1024);
                }
            __syncthreads();   // h1-region reads done (all waves) + h0 stage complete

#pragma unroll
            for (int pc = 0; pc < 2; ++pc) {
                const int cb = (kh * 2 + pc) * 16384;
#pragma unroll
                for (int kk = 0; kk < 8; ++kk) {
                    int off = cb + rl0 * 512 + ((((kk << 2) + g4) ^ xr) << 4);
                    bf16x8 a0 = *(const bf16x8*)(smem + off);
                    bf16x8 a1 = *(const bf16x8*)(smem + off + 8192);
                    acc0 = MFMA16(a0, wv0[pc * 8 + kk], acc0);
                    acc1 = MFMA16(a1, wv0[pc * 8 + kk], acc1);
                }
            }
            {
                int cbase = (g * 2 + kh) * 512 + (g4 * 4) * 16 + rl0;
#pragma unroll
                for (int r = 0; r < 4; ++r) {
                    comb[cbase + r * 16] = acc0[r];
                    comb[cbase + 256 + r * 16] = acc1[r];
                }
            }
            __syncthreads();
            {
                int e = rl * 16 + cl;
                float iv = comb[e] + comb[512 + e] + b_i;
                float fv = comb[1024 + e] + comb[1536 + e] + b_f;
                float gv = comb[2048 + e] + comb[2560 + e] + b_g;
                float ov = comb[3072 + e] + comb[3584 + e] + b_o;
                iv = sigm(iv); fv = sigm(fv); ov = sigm(ov); gv = tanh_f(gv);
                float cn = fv * c_reg + iv * gv;
                float hn = ov * tanh_f(cn);
                c_reg = cn;
                int s = ((col & 255) >> 3) ^ (grow & 7);
                stg_u16_sc(&P.h1sw[(size_t)(t & 3) * 65536 + ((col >> 8) * 64 + grow) * 256 + s * 8 + (col & 7)],
                           (unsigned int)f2bf(hn));
                P.out[((size_t)grow * 256 + t) * 1024 + col] = hn;       // outputs[b][t][h]
                if (t == TT - 1) {
                    P.out[16777216 + 65536 + grow * 1024 + col] = hn;    // h_f layer1
                    P.out[16777216 + 196608 + grow * 1024 + col] = cn;   // c_f layer1
                }
            }
            asm volatile("s_waitcnt vmcnt(0)" ::: "memory");
            __syncthreads();
            if (tid == 0) st_flag_sc(myflag, t + 1);
        }
    }
}

// ---------------- host ----------------
extern "C" void kernel_launch(void* const* d_in, const int* in_sizes, int n_in,
                              void* d_out, int out_size, void* d_ws, size_t ws_size,
                              hipStream_t stream) {
    const float* inputs = (const float*)d_in[0];
    const float* h0in = (const float*)d_in[1];
    const float* c0in = (const float*)d_in[2];
    const float* Wx0 = (const float*)d_in[3];
    const float* bx0 = (const float*)d_in[4];
    const float* Wh0 = (const float*)d_in[5];
    const float* bh0 = (const float*)d_in[6];
    const float* Wx1 = (const float*)d_in[7];
    const float* bx1 = (const float*)d_in[8];
    const float* Wh1 = (const float*)d_in[9];
    const float* bh1 = (const float*)d_in[10];
    float* out = (float*)d_out;

    char* ws = (char*)d_ws;
    unsigned short* Wh0b = (unsigned short*)(ws + ((size_t)0 << 20));
    unsigned short* Wx1b = (unsigned short*)(ws + ((size_t)8 << 20));
    unsigned short* Wh1b = (unsigned short*)(ws + ((size_t)16 << 20));
    unsigned short* Wx0b = (unsigned short*)(ws + ((size_t)24 << 20));
    unsigned short* inbf = (unsigned short*)(ws + ((size_t)32 << 20));
    unsigned short* X0pre = (unsigned short*)(ws + ((size_t)64 << 20));
    float* bias0 = (float*)(ws + ((size_t)192 << 20));
    unsigned short* h0sw = (unsigned short*)(ws + ((size_t)192 << 20) + 16384);   // 4*65536 ushorts
    unsigned short* h1sw = h0sw + 262144;
    int* flags = (int*)(h1sw + 262144);                                           // 4096 ints

    prep_kernel<<<2048, 256, 0, stream>>>(inputs, h0in, Wx0, bx0, Wh0, bh0, Wx1, Wh1,
                                          Wx0b, Wh0b, Wx1b, Wh1b, inbf, bias0, h0sw, h1sw, flags);

    gemm0_kernel<<<4096, 256, 0, stream>>>(inbf, Wx0b, bias0, X0pre);

    RecParams P;
    P.X0pre = X0pre; P.Wh0b = Wh0b; P.Wx1b = Wx1b; P.Wh1b = Wh1b;
    P.bx1 = bx1; P.bh1 = bh1; P.c0in = c0in;
    P.h0sw = h0sw; P.h1sw = h1sw; P.flags = flags; P.out = out;
    void* kargs[] = { &P };
    hipLaunchCooperativeKernel((const void*)lstm_rec, dim3(NB), dim3(NT), kargs, 0, stream);
}